// Round 4
// baseline (88.374 us; speedup 1.0000x reference)
//
#include <hip/hip_runtime.h>
#include <stdint.h>

// NeRF "mark untrained cells": out[cas][m] = visible(cas, morton_decode(m)) ? density[cas][m] : -1
// Round-3 kernel PASSED with absmax 0.0; this round keeps the decision path BIT-IDENTICAL
// while cutting VALU instructions per (cell,cam) ~66 -> ~40:
//  * S1 = 2*S0, S2 = 4*S0 EXACTLY (127/128, 254/128, 508/128). Rounding commutes with
//    exact power-of-2 scaling, so round(w*S1) = 2*round(w*S0) and the whole fma-chain dot
//    scales bit-exactly: dot(c1,R) = 2*dot(c0,R). Therefore
//      cam1_k = round(dot(c1,R)_k - d_k) = round(2*p_k - d_k) = fmaf(2.0f, p_k, -d_k)
//    (single instruction; fsub(exact(2p),d) and fma(2,p,-d) round identically).
//  * per-cascade wave-uniform skip: once __all(vk), skip cascade k's ~10 ops for the
//    remaining cameras (exact: |= into an all-true mask is a no-op).
//  * R read straight from poses with wave-uniform index -> s_load (scalar pipe), no LDS.
// fp semantics (validated round 3): cxyz rounded before dot; dots = ascending fma chains;
// the cam subtraction separately rounded; mask rhs = unfused mul+add.

constexpr int GRIDN  = 128;
constexpr int NCELLS = GRIDN * GRIDN * GRIDN;   // 2097152
constexpr int NCAMS  = 32;

__device__ __forceinline__ uint32_t compact1by2(uint32_t x) {
    // inverse of reference _part1by2 (valid for 21-bit morton codes)
    x &= 0x09249249u;
    x = (x ^ (x >> 2))  & 0x030c30c3u;
    x = (x ^ (x >> 4))  & 0x0300f00fu;
    x = (x ^ (x >> 8))  & 0x030000ffu;
    x = (x ^ (x >> 16)) & 0x000003ffu;
    return x;
}

__launch_bounds__(256)
__global__ void nerf_mark_kernel(const float* __restrict__ dg,
                                 const float* __restrict__ poses,
                                 const float* __restrict__ intr,
                                 float* __restrict__ out) {
    __shared__ float sd[NCAMS * 3];   // (t . R)[b][k], fma-chain rounding (as round 3)
    __shared__ float sw[GRIDN];       // world coord table: 2*i/127 - 1 (IEEE divide)
    __shared__ float sax[2];          // cx/fx, cy/fy

    const int tid = threadIdx.x;
    if (tid < NCAMS * 3) {
        int b = tid / 3, k = tid - b * 3;
        const float* P = poses + b * 16;
        // (t.R)[k] = fma(t2, R2k, fma(t1, R1k, t0*R0k)); t_j = P[j*4+3]
        sd[tid] = fmaf(P[11], P[8 + k], fmaf(P[7], P[4 + k], P[3] * P[k]));
    }
    if (tid < GRIDN) sw[tid] = (2.0f * (float)tid) / 127.0f - 1.0f;
    if (tid == 0) { sax[0] = intr[2] / intr[0]; sax[1] = intr[3] / intr[1]; }
    __syncthreads();

    const int m = blockIdx.x * 256 + tid;
    const uint32_t um = (uint32_t)m;
    const float wx = sw[compact1by2(um)];
    const float wy = sw[compact1by2(um >> 1)];
    const float wz = sw[compact1by2(um >> 2)];
    const float ax = sax[0], ay = sax[1];

    // cascade constants: S0 = 127/128 (exact), T = 2h (exact); S1 = 2*S0, S2 = 4*S0 exact.
    constexpr float S0 = 1.0f - 1.0f / 128.0f;
    constexpr float T0 = 2.0f / 128.0f, T1 = 4.0f / 128.0f, T2 = 8.0f / 128.0f;

    // cascade-0 cxyz, rounded before the dot (reference order)
    const float c0x = __fmul_rn(wx, S0), c0y = __fmul_rn(wy, S0), c0z = __fmul_rn(wz, S0);

    bool v0 = false, v1 = false, v2 = false;
    for (int b = 0; b < NCAMS; ++b) {
        const float* P = poses + b * 16;            // wave-uniform -> scalar loads
        const float R0 = P[0], R1 = P[1], R2 = P[2];
        const float R3 = P[4], R4 = P[5], R5 = P[6];
        const float R6 = P[8], R7 = P[9], R8 = P[10];
        const float dx = sd[b * 3], dy = sd[b * 3 + 1], dz = sd[b * 3 + 2];

        // base dot p = dot(c0, R[:,k]) as ascending fma chain (bit-identical to round 3)
        const float px = fmaf(c0z, R6, fmaf(c0y, R3, c0x * R0));
        const float py = fmaf(c0z, R7, fmaf(c0y, R4, c0x * R1));
        const float pz = fmaf(c0z, R8, fmaf(c0y, R5, c0x * R2));

        if (!__all(v0)) {
            const float zz = __fsub_rn(pz, dz);
            const float xx = __fsub_rn(px, dx);
            const float yy = __fsub_rn(py, dy);
            v0 = v0 | ((zz > 0.0f)
                     & (fabsf(xx) < __fadd_rn(__fmul_rn(ax, zz), T0))
                     & (fabsf(yy) < __fadd_rn(__fmul_rn(ay, zz), T0)));
        }
        if (!__all(v1)) {
            const float zz = fmaf(2.0f, pz, -dz);   // == round(dot(c1,Rz) - dz) exactly
            const float xx = fmaf(2.0f, px, -dx);
            const float yy = fmaf(2.0f, py, -dy);
            v1 = v1 | ((zz > 0.0f)
                     & (fabsf(xx) < __fadd_rn(__fmul_rn(ax, zz), T1))
                     & (fabsf(yy) < __fadd_rn(__fmul_rn(ay, zz), T1)));
        }
        if (!__all(v2)) {
            const float zz = fmaf(4.0f, pz, -dz);   // == round(dot(c2,Rz) - dz) exactly
            const float xx = fmaf(4.0f, px, -dx);
            const float yy = fmaf(4.0f, py, -dy);
            v2 = v2 | ((zz > 0.0f)
                     & (fabsf(xx) < __fadd_rn(__fmul_rn(ax, zz), T2))
                     & (fabsf(yy) < __fadd_rn(__fmul_rn(ay, zz), T2)));
        }
        if (__all(v0 & v1 & v2)) break;             // all lanes fully decided
    }

    out[m]              = v0 ? dg[m]              : -1.0f;
    out[NCELLS + m]     = v1 ? dg[NCELLS + m]     : -1.0f;
    out[2 * NCELLS + m] = v2 ? dg[2 * NCELLS + m] : -1.0f;
}

extern "C" void kernel_launch(void* const* d_in, const int* in_sizes, int n_in,
                              void* d_out, int out_size, void* d_ws, size_t ws_size,
                              hipStream_t stream) {
    const float* dg    = (const float*)d_in[0];   // (3, 128^3) f32
    const float* poses = (const float*)d_in[1];   // (32, 4, 4) f32
    const float* intr  = (const float*)d_in[2];   // (4,) f32
    float* out = (float*)d_out;                   // (3, 128^3) f32

    nerf_mark_kernel<<<NCELLS / 256, 256, 0, stream>>>(dg, poses, intr, out);
}

// Round 5
// 61.536 us; speedup vs baseline: 1.4361x; 1.4361x over previous
//
#include <hip/hip_runtime.h>
#include <stdint.h>

// NeRF "mark untrained cells": out[cas][m] = visible(cas, morton_decode(m)) ? density[cas][m] : -1
//
// Structure = round 3 (PASSED, 80% VALUBusy): straight-line loop body, R/t.R staged in
// LDS (wave-uniform broadcast reads), ONE __all break per iteration.
// Math = round 4 (PASSED, absmax 0.0): single dot p = dot(c0,R) shared across cascades;
// since S1=2*S0, S2=4*S0 exactly and rounding commutes with exact power-of-2 scaling,
//   cam_k(cas c) = round(2^c * p_k - d_k) = fmaf(2^c, p_k, -d_k)   (bit-identical).
// Round 4's regression (88 us, VALUBusy 48%) came from per-cascade wave-uniform BRANCHES
// + per-iteration s_load/lgkmcnt drains, not from the math -- both reverted here.
//
// fp semantics (validated on HW): c0 = round(w*S0) before the dot; dot = ascending fma
// chain; cam subtraction separately rounded (neg modifier on fma src2 is free/exact);
// mask rhs = unfused mul+add; compares use |x| via input modifier.

constexpr int GRIDN  = 128;
constexpr int NCELLS = GRIDN * GRIDN * GRIDN;   // 2097152
constexpr int NCAMS  = 32;

__device__ __forceinline__ uint32_t compact1by2(uint32_t x) {
    // inverse of reference _part1by2 (valid for 21-bit morton codes)
    x &= 0x09249249u;
    x = (x ^ (x >> 2))  & 0x030c30c3u;
    x = (x ^ (x >> 4))  & 0x0300f00fu;
    x = (x ^ (x >> 8))  & 0x030000ffu;
    x = (x ^ (x >> 16)) & 0x000003ffu;
    return x;
}

__launch_bounds__(256)
__global__ void nerf_mark_kernel(const float* __restrict__ dg,
                                 const float* __restrict__ poses,
                                 const float* __restrict__ intr,
                                 float* __restrict__ out) {
    __shared__ float sR[NCAMS * 9];   // R[b][j][k] = poses[b, j, k]
    __shared__ float sd[NCAMS * 3];   // (t . R)[b][k], fma-chain rounding
    __shared__ float sc0[GRIDN];      // c0 table: round((2i/127 - 1) * S0)
    __shared__ float sax[2];          // cx/fx, cy/fy

    constexpr float S0 = 1.0f - 1.0f / 128.0f;                        // 127/128, exact
    constexpr float T0 = 2.0f / 128.0f, T1 = 4.0f / 128.0f, T2 = 8.0f / 128.0f;

    const int tid = threadIdx.x;
    for (int i = tid; i < NCAMS * 9; i += 256) {   // 288 elems > 256 threads: strided!
        int b = i / 9, r = i - b * 9;
        int j = r / 3, k = r - j * 3;
        sR[i] = poses[b * 16 + j * 4 + k];
    }
    if (tid < NCAMS * 3) {
        int b = tid / 3, k = tid - b * 3;
        const float* P = poses + b * 16;
        // (t.R)[k] = fma(t2, R2k, fma(t1, R1k, t0*R0k)); t_j = P[j*4+3]
        sd[tid] = fmaf(P[11], P[8 + k], fmaf(P[7], P[4 + k], P[3] * P[k]));
    }
    if (tid < GRIDN) {
        // w = (2*i)/127 - 1 with IEEE div/sub (reference ufunc order), then c0 = round(w*S0)
        float w = (2.0f * (float)tid) / 127.0f - 1.0f;
        sc0[tid] = __fmul_rn(w, S0);
    }
    if (tid == 0) { sax[0] = intr[2] / intr[0]; sax[1] = intr[3] / intr[1]; }
    __syncthreads();

    const int m = blockIdx.x * 256 + tid;
    const uint32_t um = (uint32_t)m;
    const float c0x = sc0[compact1by2(um)];
    const float c0y = sc0[compact1by2(um >> 1)];
    const float c0z = sc0[compact1by2(um >> 2)];
    const float ax = sax[0], ay = sax[1];

    bool v0 = false, v1 = false, v2 = false;
    for (int b = 0; b < NCAMS; ++b) {
        const float* R = &sR[b * 9];
        const float R0 = R[0], R1 = R[1], R2 = R[2];
        const float R3 = R[3], R4 = R[4], R5 = R[5];
        const float R6 = R[6], R7 = R[7], R8 = R[8];
        const float dx = sd[b * 3], dy = sd[b * 3 + 1], dz = sd[b * 3 + 2];

        // shared dot p = dot(c0, R[:,k]), ascending fma chain (bit-identical to round 3)
        const float px = fmaf(c0z, R6, fmaf(c0y, R3, c0x * R0));
        const float py = fmaf(c0z, R7, fmaf(c0y, R4, c0x * R1));
        const float pz = fmaf(c0z, R8, fmaf(c0y, R5, c0x * R2));

        // cascade 0: cam = p - d
        {
            const float zz = __fsub_rn(pz, dz);
            const float xx = __fsub_rn(px, dx);
            const float yy = __fsub_rn(py, dy);
            v0 = v0 | ((zz > 0.0f)
                     & (fabsf(xx) < __fadd_rn(__fmul_rn(ax, zz), T0))
                     & (fabsf(yy) < __fadd_rn(__fmul_rn(ay, zz), T0)));
        }
        // cascade 1: cam = 2*p - d (exact scaling, single fma, bit-identical)
        {
            const float zz = fmaf(2.0f, pz, -dz);
            const float xx = fmaf(2.0f, px, -dx);
            const float yy = fmaf(2.0f, py, -dy);
            v1 = v1 | ((zz > 0.0f)
                     & (fabsf(xx) < __fadd_rn(__fmul_rn(ax, zz), T1))
                     & (fabsf(yy) < __fadd_rn(__fmul_rn(ay, zz), T1)));
        }
        // cascade 2: cam = 4*p - d
        {
            const float zz = fmaf(4.0f, pz, -dz);
            const float xx = fmaf(4.0f, px, -dx);
            const float yy = fmaf(4.0f, py, -dy);
            v2 = v2 | ((zz > 0.0f)
                     & (fabsf(xx) < __fadd_rn(__fmul_rn(ax, zz), T2))
                     & (fabsf(yy) < __fadd_rn(__fmul_rn(ay, zz), T2)));
        }

        if (__all(v0 & v1 & v2)) break;             // single wave-uniform early exit
    }

    out[m]              = v0 ? dg[m]              : -1.0f;
    out[NCELLS + m]     = v1 ? dg[NCELLS + m]     : -1.0f;
    out[2 * NCELLS + m] = v2 ? dg[2 * NCELLS + m] : -1.0f;
}

extern "C" void kernel_launch(void* const* d_in, const int* in_sizes, int n_in,
                              void* d_out, int out_size, void* d_ws, size_t ws_size,
                              hipStream_t stream) {
    const float* dg    = (const float*)d_in[0];   // (3, 128^3) f32
    const float* poses = (const float*)d_in[1];   // (32, 4, 4) f32
    const float* intr  = (const float*)d_in[2];   // (4,) f32
    float* out = (float*)d_out;                   // (3, 128^3) f32

    nerf_mark_kernel<<<NCELLS / 256, 256, 0, stream>>>(dg, poses, intr, out);
}